// Round 1
// baseline (557.713 us; speedup 1.0000x reference)
//
#include <hip/hip_runtime.h>

#define DD 128

// ---------------------------------------------------------------------------
// K1: per-node dot products s[n] = h[n]·aw_src, t[n] = h[n]·aw_dst
// one 64-lane wave per node, 2 floats per lane
// ---------------------------------------------------------------------------
__global__ __launch_bounds__(256) void k_node_dots(
    const float* __restrict__ h, const float* __restrict__ attn_w,
    float* __restrict__ s, float* __restrict__ t, int n_nodes)
{
    int gid  = blockIdx.x * blockDim.x + threadIdx.x;
    int node = gid >> 6;
    int lane = threadIdx.x & 63;
    if (node >= n_nodes) return;
    const float2 hv = *reinterpret_cast<const float2*>(h + (size_t)node * DD + lane * 2);
    const float2 as = *reinterpret_cast<const float2*>(attn_w + lane * 2);
    const float2 ad = *reinterpret_cast<const float2*>(attn_w + DD + lane * 2);
    float sa = hv.x * as.x + hv.y * as.y;
    float ta = hv.x * ad.x + hv.y * ad.y;
    #pragma unroll
    for (int off = 32; off > 0; off >>= 1) {
        sa += __shfl_down(sa, off);
        ta += __shfl_down(ta, off);
    }
    if (lane == 0) { s[node] = sa; t[node] = ta; }
}

// ---------------------------------------------------------------------------
// K2: per-edge score e = relu(s[src]+t[dst]+b); segment-max via uint atomicMax
// (valid because e >= 0 after relu; emax buffer pre-zeroed)
// ---------------------------------------------------------------------------
__global__ __launch_bounds__(256) void k_edge_max(
    const float* __restrict__ s, const float* __restrict__ t,
    const int* __restrict__ src, const int* __restrict__ dst,
    const float* __restrict__ attn_b, float* __restrict__ emax, int n_edges)
{
    int e = blockIdx.x * blockDim.x + threadIdx.x;
    if (e >= n_edges) return;
    int d = dst[e];
    float v = fmaxf(s[src[e]] + t[d] + attn_b[0], 0.f);
    atomicMax(reinterpret_cast<unsigned int*>(emax) + d, __float_as_uint(v));
}

// ---------------------------------------------------------------------------
// K3: per-edge p = exp(e - emax[dst]); denom[dst] += p
// ---------------------------------------------------------------------------
__global__ __launch_bounds__(256) void k_edge_exp(
    const float* __restrict__ s, const float* __restrict__ t,
    const int* __restrict__ src, const int* __restrict__ dst,
    const float* __restrict__ attn_b, const float* __restrict__ emax,
    float* __restrict__ p, float* __restrict__ denom, int n_edges)
{
    int e = blockIdx.x * blockDim.x + threadIdx.x;
    if (e >= n_edges) return;
    int d = dst[e];
    float v  = fmaxf(s[src[e]] + t[d] + attn_b[0], 0.f);
    float pe = expf(v - emax[d]);
    p[e] = pe;
    atomicAdd(denom + d, pe);
}

// ---------------------------------------------------------------------------
// K4: scatter u[dst] += p * ef   (128 threads per edge, 1 float each)
// ---------------------------------------------------------------------------
__global__ __launch_bounds__(256) void k_scatter(
    const float* __restrict__ ef, const int* __restrict__ dst,
    const float* __restrict__ p, float* __restrict__ u, int n_edges)
{
    int gid = blockIdx.x * blockDim.x + threadIdx.x;
    int e = gid >> 7;
    int j = gid & 127;
    if (e >= n_edges) return;
    float val = p[e] * ef[(size_t)e * DD + j];
    atomicAdd(u + (size_t)dst[e] * DD + j, val);
}

// ---------------------------------------------------------------------------
// K5: out[n] = relu([h[n], u[n]/denom[n]] @ W^T + b)
// 16 nodes / block, hz staged in LDS, thread owns (k, 8 nodes)
// ---------------------------------------------------------------------------
__global__ __launch_bounds__(256) void k_apply(
    const float* __restrict__ h, const float* __restrict__ u,
    const float* __restrict__ denom,
    const float* __restrict__ W, const float* __restrict__ b,
    float* __restrict__ out, int n_nodes)
{
    __shared__ float4 hz[16][64];   // 16 nodes x 256 floats (h | z)
    int n0  = blockIdx.x * 16;
    int tid = threadIdx.x;
    #pragma unroll
    for (int it = 0; it < 4; ++it) {
        int idx = tid + it * 256;       // 0..1023
        int n   = idx >> 6;
        int q   = idx & 63;
        int node = n0 + n;
        float4 v = make_float4(0.f, 0.f, 0.f, 0.f);
        if (node < n_nodes) {
            if (q < 32) {
                v = *reinterpret_cast<const float4*>(h + (size_t)node * DD + q * 4);
            } else {
                float dn  = denom[node];
                float inv = dn > 0.f ? 1.f / dn : 0.f;
                float4 uu = *reinterpret_cast<const float4*>(u + (size_t)node * DD + (q - 32) * 4);
                v = make_float4(uu.x * inv, uu.y * inv, uu.z * inv, uu.w * inv);
            }
        }
        hz[n][q] = v;
    }
    __syncthreads();

    int k = tid & 127;
    int g = tid >> 7;                 // node half: g*8 .. g*8+7
    float acc[8] = {0.f, 0.f, 0.f, 0.f, 0.f, 0.f, 0.f, 0.f};
    const float* wr = W + (size_t)k * (2 * DD);
    #pragma unroll 4
    for (int q = 0; q < 64; ++q) {
        float4 w4 = *reinterpret_cast<const float4*>(wr + q * 4);
        #pragma unroll
        for (int i = 0; i < 8; ++i) {
            float4 x = hz[g * 8 + i][q];   // same addr across wave -> broadcast
            acc[i] = fmaf(w4.x, x.x, fmaf(w4.y, x.y, fmaf(w4.z, x.z, fmaf(w4.w, x.w, acc[i]))));
        }
    }
    float bk = b[k];
    #pragma unroll
    for (int i = 0; i < 8; ++i) {
        int node = n0 + g * 8 + i;
        if (node < n_nodes)
            out[(size_t)node * DD + k] = fmaxf(acc[i] + bk, 0.f);
    }
}

// ---------------------------------------------------------------------------
extern "C" void kernel_launch(void* const* d_in, const int* in_sizes, int n_in,
                              void* d_out, int out_size, void* d_ws, size_t ws_size,
                              hipStream_t stream)
{
    const float* nfeats = (const float*)d_in[0];
    const float* efeats = (const float*)d_in[1];
    const float* W      = (const float*)d_in[2];
    const float* Wb     = (const float*)d_in[3];
    const float* attn_w = (const float*)d_in[4];
    const float* attn_b = (const float*)d_in[5];
    const int*   src    = (const int*)d_in[6];
    const int*   dst    = (const int*)d_in[7];

    const int n_nodes = in_sizes[0] / DD;
    const int n_edges = in_sizes[6];

    float* ws    = (float*)d_ws;
    float* s_buf = ws;                      // N
    float* t_buf = s_buf + n_nodes;         // N
    float* emax  = t_buf + n_nodes;         // N
    float* denom = emax + n_nodes;          // N
    float* p_buf = denom + n_nodes;         // E
    float* u_buf = p_buf + n_edges;         // N*128 (offset 4N+E floats, 16B-aligned here)
    float* out   = (float*)d_out;

    // zero emax + denom (contiguous) and the z-accumulator
    hipMemsetAsync(emax, 0, (size_t)2 * n_nodes * sizeof(float), stream);
    hipMemsetAsync(u_buf, 0, (size_t)n_nodes * DD * sizeof(float), stream);

    k_node_dots<<<(n_nodes + 3) / 4, 256, 0, stream>>>(nfeats, attn_w, s_buf, t_buf, n_nodes);
    k_edge_max<<<(n_edges + 255) / 256, 256, 0, stream>>>(s_buf, t_buf, src, dst, attn_b, emax, n_edges);
    k_edge_exp<<<(n_edges + 255) / 256, 256, 0, stream>>>(s_buf, t_buf, src, dst, attn_b, emax, p_buf, denom, n_edges);

    long long scatter_threads = (long long)n_edges * DD;
    int scatter_blocks = (int)((scatter_threads + 255) / 256);
    k_scatter<<<scatter_blocks, 256, 0, stream>>>(efeats, dst, p_buf, u_buf, n_edges);

    k_apply<<<(n_nodes + 15) / 16, 256, 0, stream>>>(nfeats, u_buf, denom, W, Wb, out, n_nodes);
}